// Round 5
// baseline (178.308 us; speedup 1.0000x reference)
//
#include <hip/hip_runtime.h>

// Problem instance constants (from reference setup_inputs): B=64, S=131072, C=3.
#define BB 64
#define SS 131072
#define WIN 100
#define TILE 4096           // positions per block
#define NTHREADS 256
#define NWAVES (NTHREADS / 64)               // 4
#define TILES_PER_ROW (SS / TILE)            // 32
#define NBLOCKS (BB * TILES_PER_ROW)         // 2048
#define EXT (TILE + 2*WIN)                   // 4296 ext-target region
#define NWORDS ((EXT + 63) / 64)             // 68 u64 pos-flag words
#define SH_BYTES (NWORDS * 64)               // 4352 (zero-padded past ext_len)
#define K4TOT (SH_BYTES / 4)                 // 1088 packed-u32 stores
#define SROUNDS ((K4TOT + NTHREADS - 1) / NTHREADS)  // 5
#define WGROUPS 4                            // groups of 256 positions per wave
#define GFLOATS 768                          // floats per group (256 pos * 3)

// Clang-native vector types: __builtin_nontemporal_load requires these.
typedef float  fx4 __attribute__((ext_vector_type(4)));
typedef int    ix4 __attribute__((ext_vector_type(4)));

// Async global->LDS DMA for one 256-position group (3072 B per wave).
// Each instruction writes LDS at wave-uniform base + lane*16 (linear), with
// the per-lane global source base + lane*16 — exactly our staging layout.
__device__ __forceinline__ void dma_group(const float* gp, float* lp, int l) {
    __builtin_amdgcn_global_load_lds(
        (const __attribute__((address_space(1))) float*)(gp + (l << 2)),
        (__attribute__((address_space(3))) float*)(lp), 16, 0, 0);
    __builtin_amdgcn_global_load_lds(
        (const __attribute__((address_space(1))) float*)(gp + 256 + (l << 2)),
        (__attribute__((address_space(3))) float*)(lp + 256), 16, 0, 0);
    __builtin_amdgcn_global_load_lds(
        (const __attribute__((address_space(1))) float*)(gp + 512 + (l << 2)),
        (__attribute__((address_space(3))) float*)(lp + 512), 16, 0, 0);
}

// Workspace: per-block slot of 4 doubles (no atomics, no memset needed):
//   slot[blk] = { masked_sum, masked_cnt, tile_unmasked_sum, tile_pos_cnt }
//
// R5 change vs R4: max occupancy via DMA staging.
//  - inputs go global->LDS via __builtin_amdgcn_global_load_lds (width 16):
//    no 12-VGPR register payload, no ds_writes -> VGPR fits the (256,8) cap.
//  - single 3 KB staging buffer per wave; block LDS ~17.4 KB -> 8 blocks/CU
//    (32 waves/CU = HW max; R4 measured occupancy as the binding resource).
//  - explicit s_waitcnt vmcnt(0) before ds_read (DMA->LDS dep), and
//    lgkmcnt(0) before re-issuing DMA into the same buffer (read-overwrite).
__global__ __launch_bounds__(NTHREADS, 8) void focal_main(
    const float* __restrict__ inputs, const int* __restrict__ targets,
    const float* __restrict__ alpha, double* __restrict__ slots)
{
    __shared__ __align__(16) unsigned char sh_t[SH_BYTES]; // target class bytes
    __shared__ unsigned long long wbits[NWORDS]; // bit i = (target[ext_lo+i]>0)
    __shared__ unsigned long long mbits[NWORDS]; // wbits dilated by +/-WIN
    __shared__ __align__(16) float lbuf[NWAVES][GFLOATS];  // 12 KB staging
    __shared__ double red[NWAVES * 4];

    const int t = threadIdx.x;
    const int w = t >> 6, l = t & 63;
    const int b = blockIdx.x / TILES_PER_ROW;
    const int tile = blockIdx.x % TILES_PER_ROW;
    const int s0 = tile * TILE;           // row-local tile start
    const int ext_lo = (s0 - WIN > 0) ? (s0 - WIN) : 0;
    const int ext_hi = (s0 + TILE + WIN < SS) ? (s0 + TILE + WIN) : SS;
    const int ext_len = ext_hi - ext_lo;  // always % 4 == 0 here
    const int tr_lo = s0 - ext_lo;        // ext-local start of exclusive tile

    // ---- issue group-0 DMA FIRST: lands in LDS during the whole preamble ----
    const float* inrow = inputs + (long)b * SS * 3;
    const float* gsrc = inrow + (long)(s0 + w * 1024) * 3;  // this wave's 12 KB
    float* lbase = &lbuf[w][0];
    dma_group(gsrc, lbase, l);

    // ---- stage targets as packed bytes via NT int4 loads (zero-pad tail) ----
    const int* trow = targets + (long)b * SS;
    #pragma unroll
    for (int it = 0; it < SROUNDS; ++it) {
        const int k4 = it * NTHREADS + t;           // u32 slot in sh_t
        if (k4 < K4TOT) {
            unsigned int pk = 0;
            if (4 * k4 < ext_len) {                 // ext_len%4==0 -> full int4
                const ix4 tv4 =
                    __builtin_nontemporal_load((const ix4*)(trow + ext_lo + 4 * k4));
                pk = (unsigned)(tv4.x & 3) | ((unsigned)(tv4.y & 3) << 8) |
                     ((unsigned)(tv4.z & 3) << 16) | ((unsigned)(tv4.w & 3) << 24);
            }
            ((unsigned int*)sh_t)[k4] = pk;
        }
    }
    __syncthreads();

    // ---- build wbits: one u64 word per thread (t < 68), from LDS bytes ----
    int cnt_p = 0;                          // positives in exclusive tile region
    if (t < NWORDS) {
        const uint4* qp = (const uint4*)(sh_t + (t << 6));
        unsigned long long wv = 0;
        #pragma unroll
        for (int r = 0; r < 4; ++r) {
            const uint4 u = qp[r];
            unsigned int x, nz;
            x = u.x; nz = (x | (x >> 1)) & 0x01010101u;
            wv |= (unsigned long long)((nz * 0x01020408u) >> 24) << (r*16 + 0);
            x = u.y; nz = (x | (x >> 1)) & 0x01010101u;
            wv |= (unsigned long long)((nz * 0x01020408u) >> 24) << (r*16 + 4);
            x = u.z; nz = (x | (x >> 1)) & 0x01010101u;
            wv |= (unsigned long long)((nz * 0x01020408u) >> 24) << (r*16 + 8);
            x = u.w; nz = (x | (x >> 1)) & 0x01010101u;
            wv |= (unsigned long long)((nz * 0x01020408u) >> 24) << (r*16 + 12);
        }
        wbits[t] = wv;
        int lo_bit = tr_lo - (t << 6);        if (lo_bit < 0) lo_bit = 0;
        int hi_bit = tr_lo + TILE - (t << 6); if (hi_bit > 64) hi_bit = 64;
        if (hi_bit > lo_bit) {
            unsigned long long rm = (hi_bit >= 64) ? ~0ULL : ((1ULL << hi_bit) - 1);
            rm &= (~0ULL << lo_bit);
            cnt_p = __popcll(wv & rm);
        }
    }
    __syncthreads();

    // ---- exact closed-form dilation by +/-100 per word (t < 68) ----
    if (t < NWORDS) {
        const unsigned long long a = (t >= 2) ? wbits[t-2] : 0ULL;
        const unsigned long long bw = (t >= 1) ? wbits[t-1] : 0ULL;
        const unsigned long long c = wbits[t];
        const unsigned long long d = (t+1 < NWORDS) ? wbits[t+1] : 0ULL;
        const unsigned long long e = (t+2 < NWORDS) ? wbits[t+2] : 0ULL;
        unsigned long long m = c ? ~0ULL : 0ULL;
        if (d) { const int lo = __builtin_ctzll(d) - 36;
                 m |= (lo <= 0) ? ~0ULL : (~0ULL << lo); }
        if (e) { const int lo = __builtin_ctzll(e) + 28;
                 if (lo <= 63) m |= (~0ULL << lo); }
        if (bw) { const int hi = 63 - __builtin_clzll(bw) + 36;
                  m |= (hi >= 63) ? ~0ULL : (~0ULL >> (63 - hi)); }
        if (a) { const int hi = 63 - __builtin_clzll(a) - 28;
                 if (hi >= 0) m |= (hi >= 63) ? ~0ULL : (~0ULL >> (63 - hi)); }
        mbits[t] = m;
    }
    __syncthreads();   // LAST block barrier before the reduce: waves drift free
                       // (also drains vmcnt -> group-0 DMA data is in LDS)

    // ---- barrier-free main loop: 4 groups of 256 positions per wave ----
    const float a0 = alpha[0], a1 = alpha[1], a2 = alpha[2];
    float fsum_m = 0.0f, fsum_a = 0.0f;
    int cnt_m = 0;
    const fx4* lread = (const fx4*)lbase;

    #pragma unroll
    for (int g = 0; g < WGROUPS; ++g) {
        // group g's DMA data is in LDS once vmcnt==0 (g=0: drained at barrier)
        asm volatile("s_waitcnt vmcnt(0)" ::: "memory");
        const fx4 c0 = lread[3 * l];
        const fx4 c1 = lread[3 * l + 1];
        const fx4 c2 = lread[3 * l + 2];
        // reads complete -> safe to overwrite the buffer with group g+1
        asm volatile("s_waitcnt lgkmcnt(0)" ::: "memory");
        if (g + 1 < WGROUPS)
            dma_group(gsrc + (g + 1) * GFLOATS, lbase, l);

        const int j0 = tr_lo + w * 1024 + g * 256 + l * 4;
        const unsigned long long mw = mbits[j0 >> 6];
        const unsigned int tpack = *(const unsigned int*)(sh_t + j0);
        const float xs[12] = {c0.x, c0.y, c0.z, c0.w, c1.x, c1.y, c1.z, c1.w,
                              c2.x, c2.y, c2.z, c2.w};
        #pragma unroll
        for (int j = 0; j < 4; ++j) {
            const float x0 = xs[3*j], x1 = xs[3*j+1], x2 = xs[3*j+2];
            const int tv = (tpack >> (8 * j)) & 0xFF;
            const float mx = fmaxf(x0, fmaxf(x1, x2));
            const float mn = fminf(x0, fminf(x1, x2));
            const float md = fmaxf(fminf(x0, x1), fminf(fmaxf(x0, x1), x2));
            const float emd = __expf(md - mx);
            const float emn = __expf(mn - mx);
            const float sum = 1.0f + emd + emn;
            const float xt  = (tv == 0) ? x0 : ((tv == 1) ? x1 : x2);
            const float ce  = __logf(sum) + (mx - xt);
            const float pt  = __expf(-ce);          // == reference p_t
            const float wgt = (tv == 0) ? a0 : ((tv == 1) ? a1 : a2);
            const float om  = 1.0f - pt;
            const float focal = wgt * om * om * ce;
            const bool  msk = (mw >> ((j0 & 63) + j)) & 1ULL;
            fsum_a += focal;
            fsum_m += msk ? focal : 0.0f;
            cnt_m  += msk ? 1 : 0;
        }
    }

    // ---- block reduce + ONE plain store per block (no atomics) ----
    #pragma unroll
    for (int off = 32; off >= 1; off >>= 1) {
        fsum_m += __shfl_down(fsum_m, off);
        fsum_a += __shfl_down(fsum_a, off);
        cnt_m  += __shfl_down(cnt_m, off);
        cnt_p  += __shfl_down(cnt_p, off);
    }
    if (l == 0) {
        red[w*4]   = (double)fsum_m; red[w*4+1] = (double)cnt_m;
        red[w*4+2] = (double)fsum_a; red[w*4+3] = (double)cnt_p;
    }
    __syncthreads();
    if (t == 0) {
        double sm = 0, sc = 0, sa = 0, sp = 0;
        #pragma unroll
        for (int v = 0; v < NWAVES; ++v) {
            sm += red[v*4]; sc += red[v*4+1]; sa += red[v*4+2]; sp += red[v*4+3];
        }
        double* slot = slots + (long)blockIdx.x * 4;
        slot[0] = sm;
        slot[1] = sc;
        slot[2] = sa;
        slot[3] = sp;
    }
}

__global__ __launch_bounds__(1024) void focal_final(
    const double* __restrict__ slots, float* __restrict__ out)
{
    __shared__ double redA[16 * 2];
    __shared__ double crs[BB];
    __shared__ double crc[BB];
    const int t = threadIdx.x;
    const int wave = t >> 6, lane = t & 63;

    // Phase A: global masked sum/count over all 2048 slots (2 per thread)
    double sm = 0.0, sc = 0.0;
    for (int k = t; k < NBLOCKS; k += 1024) {
        sm += slots[(long)k * 4 + 0];
        sc += slots[(long)k * 4 + 1];
    }
    #pragma unroll
    for (int off = 32; off >= 1; off >>= 1) {
        sm += __shfl_down(sm, off);
        sc += __shfl_down(sc, off);
    }
    if (lane == 0) { redA[wave*2] = sm; redA[wave*2+1] = sc; }

    // Phase B: per-row "no positives" correction — 16 threads per row,
    // 2 tile-slots each (64 rows * 32 tiles = 2048 = 1024 * 2).
    const int row = t >> 4;              // 0..63
    const int rpart = t & 15;            // which pair of tiles
    const long base = (long)row * TILES_PER_ROW + rpart * 2;
    double rs = slots[base*4 + 2] + slots[(base+1)*4 + 2];
    double rp = slots[base*4 + 3] + slots[(base+1)*4 + 3];
    #pragma unroll
    for (int off = 8; off >= 1; off >>= 1) {
        rs += __shfl_down(rs, off, 16);
        rp += __shfl_down(rp, off, 16);
    }
    if (rpart == 0) { crs[row] = rs; crc[row] = rp; }
    __syncthreads();

    if (t == 0) {
        double a = 0.0, bsum = 0.0;
        #pragma unroll
        for (int v = 0; v < 16; ++v) { a += redA[v*2]; bsum += redA[v*2+1]; }
        double corr_s = 0.0, corr_c = 0.0;
        #pragma unroll
        for (int r = 0; r < BB; ++r) {
            if (crc[r] == 0.0) { corr_s += crs[r]; corr_c += (double)SS; }
        }
        out[0] = (float)((a + corr_s) / (bsum + corr_c));
    }
}

extern "C" void kernel_launch(void* const* d_in, const int* in_sizes, int n_in,
                              void* d_out, int out_size, void* d_ws, size_t ws_size,
                              hipStream_t stream) {
    const float* inputs  = (const float*)d_in[0];
    const int*   targets = (const int*)d_in[1];
    const float* alpha   = (const float*)d_in[2];
    float* out = (float*)d_out;

    double* slots = (double*)d_ws;   // NBLOCKS * 4 doubles = 64 KB, all written

    focal_main<<<NBLOCKS, NTHREADS, 0, stream>>>(inputs, targets, alpha, slots);
    focal_final<<<1, 1024, 0, stream>>>(slots, out);
}

// Round 6
// 165.385 us; speedup vs baseline: 1.0781x; 1.0781x over previous
//
#include <hip/hip_runtime.h>

// Problem instance constants (from reference setup_inputs): B=64, S=131072, C=3.
#define BB 64
#define SS 131072
#define WIN 100
#define TILE 4096           // positions per block
#define NTHREADS 256
#define NWAVES (NTHREADS / 64)               // 4
#define TILES_PER_ROW (SS / TILE)            // 32
#define NBLOCKS (BB * TILES_PER_ROW)         // 2048
#define EXT (TILE + 2*WIN)                   // 4296 ext-target region
#define NWORDS ((EXT + 63) / 64)             // 68 u64 pos-flag words
#define SH_BYTES (NWORDS * 64)               // 4352 (zero-padded past ext_len)
#define K4TOT (SH_BYTES / 4)                 // 1088 packed-u32 stores
#define SROUNDS ((K4TOT + NTHREADS - 1) / NTHREADS)  // 5
#define WGROUPS 4                            // groups of 256 positions per wave
#define GF4 192                              // fx4 per group (256 pos * 3 / 4)

// Clang-native vector types: __builtin_nontemporal_load requires these.
typedef float  fx4 __attribute__((ext_vector_type(4)));
typedef int    ix4 __attribute__((ext_vector_type(4)));

// Workspace: per-block slot of 4 doubles (no atomics, no memset needed):
//   slot[blk] = { masked_sum, masked_cnt, tile_unmasked_sum, tile_pos_cnt }
//
// R6 = R4 structure (register staging + single-buffer LDS layout-fix +
// barrier-free main loop) with a register diet to reach 7 waves/EU:
//  - cnt_m moved out of the inner loop: masked count = popcount(mbits & tile
//    range), computed in the t<NWORDS dilation phase next to cnt_p.
//  - sorting network via v_max3/v_min3 fusion + __builtin_amdgcn_fmed3f.
//  - launch_bounds (256,7): VGPR cap 72 (R5 proved 64 spills; R4 ran at 85).
__global__ __launch_bounds__(NTHREADS, 7) void focal_main(
    const float* __restrict__ inputs, const int* __restrict__ targets,
    const float* __restrict__ alpha, double* __restrict__ slots)
{
    __shared__ __align__(16) unsigned char sh_t[SH_BYTES]; // target class bytes
    __shared__ unsigned long long wbits[NWORDS]; // bit i = (target[ext_lo+i]>0)
    __shared__ unsigned long long mbits[NWORDS]; // wbits dilated by +/-WIN
    __shared__ fx4 lbuf[NWAVES][GF4];            // 12 KB: per-wave SINGLE buf
    __shared__ double red[NWAVES * 4];

    const int t = threadIdx.x;
    const int w = t >> 6, l = t & 63;
    const int b = blockIdx.x / TILES_PER_ROW;
    const int tile = blockIdx.x % TILES_PER_ROW;
    const int s0 = tile * TILE;           // row-local tile start
    const int ext_lo = (s0 - WIN > 0) ? (s0 - WIN) : 0;
    const int ext_hi = (s0 + TILE + WIN < SS) ? (s0 + TILE + WIN) : SS;
    const int ext_len = ext_hi - ext_lo;  // always % 4 == 0 here
    const int tr_lo = s0 - ext_lo;        // ext-local start of exclusive tile

    // ---- issue group-0 coalesced NT loads FIRST: latency hides under the
    //      whole target-staging + mask-build preamble ----
    const float* inrow = inputs + (long)b * SS * 3;
    const fx4* gsrc = (const fx4*)(inrow + (long)(s0 + w * 1024) * 3); // 768 fx4
    fx4 q0 = __builtin_nontemporal_load(gsrc + l);
    fx4 q1 = __builtin_nontemporal_load(gsrc + 64 + l);
    fx4 q2 = __builtin_nontemporal_load(gsrc + 128 + l);

    // ---- stage targets as packed bytes via NT int4 loads (zero-pad tail) ----
    const int* trow = targets + (long)b * SS;
    #pragma unroll
    for (int it = 0; it < SROUNDS; ++it) {
        const int k4 = it * NTHREADS + t;           // u32 slot in sh_t
        if (k4 < K4TOT) {
            unsigned int pk = 0;
            if (4 * k4 < ext_len) {                 // ext_len%4==0 -> full int4
                const ix4 tv4 =
                    __builtin_nontemporal_load((const ix4*)(trow + ext_lo + 4 * k4));
                pk = (unsigned)(tv4.x & 3) | ((unsigned)(tv4.y & 3) << 8) |
                     ((unsigned)(tv4.z & 3) << 16) | ((unsigned)(tv4.w & 3) << 24);
            }
            ((unsigned int*)sh_t)[k4] = pk;
        }
    }
    __syncthreads();

    // ---- build wbits: one u64 word per thread (t < 68), from LDS bytes ----
    int cnt_p = 0;                     // positives in exclusive tile region
    int cnt_m = 0;                     // masked positions (filled after dilate)
    unsigned long long rm_keep = 0;    // tile-range mask for this word
    if (t < NWORDS) {
        const uint4* qp = (const uint4*)(sh_t + (t << 6));
        unsigned long long wv = 0;
        #pragma unroll
        for (int r = 0; r < 4; ++r) {
            const uint4 u = qp[r];
            unsigned int x, nz;
            x = u.x; nz = (x | (x >> 1)) & 0x01010101u;
            wv |= (unsigned long long)((nz * 0x01020408u) >> 24) << (r*16 + 0);
            x = u.y; nz = (x | (x >> 1)) & 0x01010101u;
            wv |= (unsigned long long)((nz * 0x01020408u) >> 24) << (r*16 + 4);
            x = u.z; nz = (x | (x >> 1)) & 0x01010101u;
            wv |= (unsigned long long)((nz * 0x01020408u) >> 24) << (r*16 + 8);
            x = u.w; nz = (x | (x >> 1)) & 0x01010101u;
            wv |= (unsigned long long)((nz * 0x01020408u) >> 24) << (r*16 + 12);
        }
        wbits[t] = wv;
        int lo_bit = tr_lo - (t << 6);        if (lo_bit < 0) lo_bit = 0;
        int hi_bit = tr_lo + TILE - (t << 6); if (hi_bit > 64) hi_bit = 64;
        if (hi_bit > lo_bit) {
            unsigned long long rm = (hi_bit >= 64) ? ~0ULL : ((1ULL << hi_bit) - 1);
            rm &= (~0ULL << lo_bit);
            rm_keep = rm;
            cnt_p = __popcll(wv & rm);
        }
    }
    __syncthreads();

    // ---- exact closed-form dilation by +/-100 per word (t < 68) ----
    if (t < NWORDS) {
        const unsigned long long a = (t >= 2) ? wbits[t-2] : 0ULL;
        const unsigned long long bw = (t >= 1) ? wbits[t-1] : 0ULL;
        const unsigned long long c = wbits[t];
        const unsigned long long d = (t+1 < NWORDS) ? wbits[t+1] : 0ULL;
        const unsigned long long e = (t+2 < NWORDS) ? wbits[t+2] : 0ULL;
        unsigned long long m = c ? ~0ULL : 0ULL;
        if (d) { const int lo = __builtin_ctzll(d) - 36;
                 m |= (lo <= 0) ? ~0ULL : (~0ULL << lo); }
        if (e) { const int lo = __builtin_ctzll(e) + 28;
                 if (lo <= 63) m |= (~0ULL << lo); }
        if (bw) { const int hi = 63 - __builtin_clzll(bw) + 36;
                  m |= (hi >= 63) ? ~0ULL : (~0ULL >> (63 - hi)); }
        if (a) { const int hi = 63 - __builtin_clzll(a) - 28;
                 if (hi >= 0) m |= (hi >= 63) ? ~0ULL : (~0ULL >> (63 - hi)); }
        mbits[t] = m;
        cnt_m = __popcll(m & rm_keep);   // masked positions in this word's tile range
    }
    __syncthreads();   // LAST block barrier before the reduce: waves drift free

    // ---- barrier-free main loop: 4 groups of 256 positions per wave ----
    const float a0 = alpha[0], a1 = alpha[1], a2 = alpha[2];
    float fsum_m = 0.0f, fsum_a = 0.0f;

    #pragma unroll
    for (int g = 0; g < WGROUPS; ++g) {
        fx4* pb = lbuf[w];
        // commit this group's coalesced payload to the wave-private buffer
        // (in-wave LDS is in-order: last group's reads already completed)
        pb[l] = q0; pb[64 + l] = q1; pb[128 + l] = q2;
        // issue next group's coalesced NT loads: they fly during the LDS
        // round-trip + compute below (no barrier ever drains them)
        if (g + 1 < WGROUPS) {
            const fx4* gn = gsrc + (g + 1) * GF4;
            q0 = __builtin_nontemporal_load(gn + l);
            q1 = __builtin_nontemporal_load(gn + 64 + l);
            q2 = __builtin_nontemporal_load(gn + 128 + l);
        }
        // layout fix: 48 B per lane, stride-48 b128 reads are bank-phase-clean
        const fx4 c0 = pb[3 * l];
        const fx4 c1 = pb[3 * l + 1];
        const fx4 c2 = pb[3 * l + 2];

        const int j0 = tr_lo + w * 1024 + g * 256 + l * 4;
        const unsigned long long mw = mbits[j0 >> 6];
        const unsigned int tpack = *(const unsigned int*)(sh_t + j0);
        const float xs[12] = {c0.x, c0.y, c0.z, c0.w, c1.x, c1.y, c1.z, c1.w,
                              c2.x, c2.y, c2.z, c2.w};
        #pragma unroll
        for (int j = 0; j < 4; ++j) {
            const float x0 = xs[3*j], x1 = xs[3*j+1], x2 = xs[3*j+2];
            const int tv = (tpack >> (8 * j)) & 0xFF;
            // v_max3 / v_min3 / v_med3: 3 ops replace the 6-op sort network
            const float mx = fmaxf(x0, fmaxf(x1, x2));
            const float mn = fminf(x0, fminf(x1, x2));
            const float md = __builtin_amdgcn_fmed3f(x0, x1, x2);
            const float emd = __expf(md - mx);
            const float emn = __expf(mn - mx);
            const float sum = 1.0f + emd + emn;
            const float xt  = (tv == 0) ? x0 : ((tv == 1) ? x1 : x2);
            const float ce  = __logf(sum) + (mx - xt);
            const float pt  = __expf(-ce);          // == reference p_t
            const float wgt = (tv == 0) ? a0 : ((tv == 1) ? a1 : a2);
            const float om  = 1.0f - pt;
            const float focal = wgt * om * om * ce;
            const bool  msk = (mw >> ((j0 & 63) + j)) & 1ULL;
            fsum_a += focal;
            fsum_m += msk ? focal : 0.0f;
        }
    }

    // ---- block reduce + ONE plain store per block (no atomics) ----
    #pragma unroll
    for (int off = 32; off >= 1; off >>= 1) {
        fsum_m += __shfl_down(fsum_m, off);
        fsum_a += __shfl_down(fsum_a, off);
        cnt_m  += __shfl_down(cnt_m, off);
        cnt_p  += __shfl_down(cnt_p, off);
    }
    if (l == 0) {
        red[w*4]   = (double)fsum_m; red[w*4+1] = (double)cnt_m;
        red[w*4+2] = (double)fsum_a; red[w*4+3] = (double)cnt_p;
    }
    __syncthreads();
    if (t == 0) {
        double sm = 0, sc = 0, sa = 0, sp = 0;
        #pragma unroll
        for (int v = 0; v < NWAVES; ++v) {
            sm += red[v*4]; sc += red[v*4+1]; sa += red[v*4+2]; sp += red[v*4+3];
        }
        double* slot = slots + (long)blockIdx.x * 4;
        slot[0] = sm;
        slot[1] = sc;
        slot[2] = sa;
        slot[3] = sp;
    }
}

__global__ __launch_bounds__(1024) void focal_final(
    const double* __restrict__ slots, float* __restrict__ out)
{
    __shared__ double redA[16 * 2];
    __shared__ double crs[BB];
    __shared__ double crc[BB];
    const int t = threadIdx.x;
    const int wave = t >> 6, lane = t & 63;

    // Phase A: global masked sum/count over all 2048 slots (2 per thread)
    double sm = 0.0, sc = 0.0;
    for (int k = t; k < NBLOCKS; k += 1024) {
        sm += slots[(long)k * 4 + 0];
        sc += slots[(long)k * 4 + 1];
    }
    #pragma unroll
    for (int off = 32; off >= 1; off >>= 1) {
        sm += __shfl_down(sm, off);
        sc += __shfl_down(sc, off);
    }
    if (lane == 0) { redA[wave*2] = sm; redA[wave*2+1] = sc; }

    // Phase B: per-row "no positives" correction — 16 threads per row,
    // 2 tile-slots each (64 rows * 32 tiles = 2048 = 1024 * 2).
    const int row = t >> 4;              // 0..63
    const int rpart = t & 15;            // which pair of tiles
    const long base = (long)row * TILES_PER_ROW + rpart * 2;
    double rs = slots[base*4 + 2] + slots[(base+1)*4 + 2];
    double rp = slots[base*4 + 3] + slots[(base+1)*4 + 3];
    #pragma unroll
    for (int off = 8; off >= 1; off >>= 1) {
        rs += __shfl_down(rs, off, 16);
        rp += __shfl_down(rp, off, 16);
    }
    if (rpart == 0) { crs[row] = rs; crc[row] = rp; }
    __syncthreads();

    if (t == 0) {
        double a = 0.0, bsum = 0.0;
        #pragma unroll
        for (int v = 0; v < 16; ++v) { a += redA[v*2]; bsum += redA[v*2+1]; }
        double corr_s = 0.0, corr_c = 0.0;
        #pragma unroll
        for (int r = 0; r < BB; ++r) {
            if (crc[r] == 0.0) { corr_s += crs[r]; corr_c += (double)SS; }
        }
        out[0] = (float)((a + corr_s) / (bsum + corr_c));
    }
}

extern "C" void kernel_launch(void* const* d_in, const int* in_sizes, int n_in,
                              void* d_out, int out_size, void* d_ws, size_t ws_size,
                              hipStream_t stream) {
    const float* inputs  = (const float*)d_in[0];
    const int*   targets = (const int*)d_in[1];
    const float* alpha   = (const float*)d_in[2];
    float* out = (float*)d_out;

    double* slots = (double*)d_ws;   // NBLOCKS * 4 doubles = 64 KB, all written

    focal_main<<<NBLOCKS, NTHREADS, 0, stream>>>(inputs, targets, alpha, slots);
    focal_final<<<1, 1024, 0, stream>>>(slots, out);
}